// Round 1
// baseline (258.275 us; speedup 1.0000x reference)
//
#include <hip/hip_runtime.h>

// MultiHeadsSelfAttention: B=2, N=2048, C=1024, H=16, D=64, SCALE=0.125
// Pipeline (all fp16 MFMA, fp32 accum/softmax):
//   cvt x,W* -> fp16 ; QKV NT-GEMM -> Q,K,V [bh][n][d] (Q pre-scaled by 2^-3)
//   V transpose -> Vt [bh][d][n] ; flash attention -> AO fp16 [b][n][c]
//   final NT-GEMM AO@Wo^T + bo -> fp32 out

typedef _Float16 h8 __attribute__((ext_vector_type(8)));
typedef _Float16 h4 __attribute__((ext_vector_type(4)));
typedef float f4 __attribute__((ext_vector_type(4)));

#define AS1(p) ((const __attribute__((address_space(1))) void*)(p))
#define AS3(p) ((__attribute__((address_space(3))) void*)(p))

// Stage 128 rows x 64 halves (128B rows, 8 x 16B chunks, XOR swizzle) via global_load_lds.
__device__ __forceinline__ void stage64(const _Float16* g, int ldk, _Float16* s, int tid) {
#pragma unroll
  for (int j = 0; j < 4; ++j) {
    int off = j * 4096 + tid * 16;      // byte offset in 16KB tile; wave-uniform base + lane*16
    int row = off >> 7;
    int ch = (off >> 4) & 7;
    int gch = ch ^ (row & 7);
    __builtin_amdgcn_global_load_lds(AS1(g + row * ldk + gch * 8), AS3(s + (off >> 1)), 16, 0, 0);
  }
}

// Stage 64 rows x 128 halves (256B rows, 16 x 16B chunks, XOR swizzle); global row stride 2048.
__device__ __forceinline__ void stage_vt(const _Float16* g, _Float16* s, int tid) {
#pragma unroll
  for (int j = 0; j < 4; ++j) {
    int off = j * 4096 + tid * 16;
    int row = off >> 8;
    int ch = (off >> 4) & 15;
    int gch = ch ^ (row & 15);
    __builtin_amdgcn_global_load_lds(AS1(g + row * 2048 + gch * 8), AS3(s + (off >> 1)), 16, 0, 0);
  }
}

__device__ __forceinline__ h8 frag64(const _Float16* s, int row, int g) {
  return *(const h8*)(s + row * 64 + ((g ^ (row & 7)) << 3));
}
__device__ __forceinline__ h8 frag128(const _Float16* s, int row, int g) {
  return *(const h8*)(s + row * 128 + ((g ^ (row & 15)) << 3));
}

__global__ void cvt_f2h(const float* __restrict__ in, _Float16* __restrict__ out, int n) {
  int i = (blockIdx.x * 256 + threadIdx.x) * 4;
  if (i >= n) return;
  f4 v = *(const f4*)(in + i);
  h4 o;
  o[0] = (_Float16)v[0]; o[1] = (_Float16)v[1]; o[2] = (_Float16)v[2]; o[3] = (_Float16)v[3];
  *(h4*)(out + i) = o;
}

// NT GEMM: C[m][o] = sum_k A[m,k]*W[o,k] + bias[o]; scatter fp16 out to [b][h][n][d].
__global__ __launch_bounds__(256, 2) void gemm_qkv(
    const _Float16* __restrict__ X,
    const _Float16* __restrict__ W0, const _Float16* __restrict__ W1, const _Float16* __restrict__ W2,
    const float* __restrict__ b0, const float* __restrict__ b1, const float* __restrict__ b2,
    _Float16* __restrict__ O0, _Float16* __restrict__ O1, _Float16* __restrict__ O2) {
  __shared__ _Float16 As[128 * 64];
  __shared__ _Float16 Bs[128 * 64];
  int z = blockIdx.z;
  const _Float16* W = (z == 0) ? W0 : (z == 1) ? W1 : W2;
  const float* bias = (z == 0) ? b0 : (z == 1) ? b1 : b2;
  _Float16* Out = (z == 0) ? O0 : (z == 1) ? O1 : O2;
  float scale = (z == 0) ? 0.125f : 1.0f;  // fold SCALE=D^-0.5 into Q (exact pow2)

  int tid = threadIdx.x;
  int lane = tid & 63, wave = tid >> 6;
  int quad = lane >> 4, l15 = lane & 15;
  int wm = (wave >> 1) << 6, wn = (wave & 1) << 6;
  int m0 = blockIdx.y << 7, n0 = blockIdx.x << 7;

  f4 acc[4][4] = {};
  for (int k0 = 0; k0 < 1024; k0 += 64) {
    stage64(X + m0 * 1024 + k0, 1024, As, tid);
    stage64(W + n0 * 1024 + k0, 1024, Bs, tid);
    __syncthreads();
#pragma unroll
    for (int ks = 0; ks < 2; ++ks) {
      h8 af[4], bf[4];
#pragma unroll
      for (int i = 0; i < 4; ++i) af[i] = frag64(As, wm + i * 16 + l15, ks * 4 + quad);
#pragma unroll
      for (int i = 0; i < 4; ++i) bf[i] = frag64(Bs, wn + i * 16 + l15, ks * 4 + quad);
#pragma unroll
      for (int mi = 0; mi < 4; ++mi)
#pragma unroll
        for (int ni = 0; ni < 4; ++ni)
          acc[mi][ni] = __builtin_amdgcn_mfma_f32_16x16x32_f16(af[mi], bf[ni], acc[mi][ni], 0, 0, 0);
    }
    __syncthreads();
  }
#pragma unroll
  for (int mi = 0; mi < 4; ++mi) {
#pragma unroll
    for (int ni = 0; ni < 4; ++ni) {
      int o = n0 + wn + ni * 16 + l15;
      float bv = bias[o];
      int h = o >> 6, d = o & 63;
#pragma unroll
      for (int r = 0; r < 4; ++r) {
        int m = m0 + wm + mi * 16 + quad * 4 + r;   // C layout: col=lane&15, row=quad*4+reg
        int b = m >> 11, n = m & 2047;
        float v = (acc[mi][ni][r] + bv) * scale;
        Out[(((b * 16 + h) * 2048 + n) << 6) + d] = (_Float16)v;
      }
    }
  }
}

// Final NT GEMM: out fp32 [m][1024].
__global__ __launch_bounds__(256, 2) void gemm_out(
    const _Float16* __restrict__ A, const _Float16* __restrict__ W,
    const float* __restrict__ bias, float* __restrict__ Out) {
  __shared__ _Float16 As[128 * 64];
  __shared__ _Float16 Bs[128 * 64];
  int tid = threadIdx.x;
  int lane = tid & 63, wave = tid >> 6;
  int quad = lane >> 4, l15 = lane & 15;
  int wm = (wave >> 1) << 6, wn = (wave & 1) << 6;
  int m0 = blockIdx.y << 7, n0 = blockIdx.x << 7;

  f4 acc[4][4] = {};
  for (int k0 = 0; k0 < 1024; k0 += 64) {
    stage64(A + m0 * 1024 + k0, 1024, As, tid);
    stage64(W + n0 * 1024 + k0, 1024, Bs, tid);
    __syncthreads();
#pragma unroll
    for (int ks = 0; ks < 2; ++ks) {
      h8 af[4], bf[4];
#pragma unroll
      for (int i = 0; i < 4; ++i) af[i] = frag64(As, wm + i * 16 + l15, ks * 4 + quad);
#pragma unroll
      for (int i = 0; i < 4; ++i) bf[i] = frag64(Bs, wn + i * 16 + l15, ks * 4 + quad);
#pragma unroll
      for (int mi = 0; mi < 4; ++mi)
#pragma unroll
        for (int ni = 0; ni < 4; ++ni)
          acc[mi][ni] = __builtin_amdgcn_mfma_f32_16x16x32_f16(af[mi], bf[ni], acc[mi][ni], 0, 0, 0);
    }
    __syncthreads();
  }
#pragma unroll
  for (int mi = 0; mi < 4; ++mi) {
#pragma unroll
    for (int ni = 0; ni < 4; ++ni) {
      int o = n0 + wn + ni * 16 + l15;
      float bv = bias[o];
#pragma unroll
      for (int r = 0; r < 4; ++r) {
        int m = m0 + wm + mi * 16 + quad * 4 + r;
        Out[m * 1024 + o] = acc[mi][ni][r] + bv;
      }
    }
  }
}

// V [bh][n][d] -> Vt [bh][d][n], 128-key tiles, LDS chunk-swizzled transpose.
__global__ __launch_bounds__(256) void transpose_v(const _Float16* __restrict__ V,
                                                   _Float16* __restrict__ Vt) {
  __shared__ _Float16 t[64 * 128];
  int tid = threadIdx.x;
  int bh = blockIdx.y, n0 = blockIdx.x << 7;
  const _Float16* src = V + (bh * 2048 + n0) * 64;
#pragma unroll
  for (int j = 0; j < 4; ++j) {
    int c = j * 256 + tid;
    int n = c >> 3, dc = (c & 7) * 8;
    h8 v = *(const h8*)(src + n * 64 + dc);
#pragma unroll
    for (int e = 0; e < 8; ++e) {
      int d = dc + e;
      t[d * 128 + ((((n >> 3) ^ (d & 15))) << 3) + (n & 7)] = v[e];
    }
  }
  __syncthreads();
#pragma unroll
  for (int j = 0; j < 4; ++j) {
    int c = j * 256 + tid;
    int d = c >> 4, nc = (c & 15) * 8;
    h8 v = *(const h8*)(t + d * 128 + ((((nc >> 3) ^ (d & 15))) << 3));
    *(h8*)(Vt + (bh * 64 + d) * 2048 + n0 + nc) = v;
  }
}

// Flash attention: per (bh, 128-row q tile); 4 waves x 32 q-rows; 128-key tiles.
__global__ __launch_bounds__(256, 2) void attn(
    const _Float16* __restrict__ Q, const _Float16* __restrict__ Kv,
    const _Float16* __restrict__ Vt, _Float16* __restrict__ AO) {
  __shared__ _Float16 Ks[128 * 64];
  __shared__ _Float16 Vs[64 * 128];
  __shared__ _Float16 Ps[4][32 * 128];
  int tid = threadIdx.x, lane = tid & 63, wave = tid >> 6;
  int quad = lane >> 4, l15 = lane & 15;
  int bh = blockIdx.y, q0 = blockIdx.x << 7;

  const _Float16* Qb = Q + (bh * 2048 + q0 + wave * 32) * 64;
  h8 qf[2][2];
#pragma unroll
  for (int mi = 0; mi < 2; ++mi)
#pragma unroll
    for (int ks = 0; ks < 2; ++ks)
      qf[mi][ks] = *(const h8*)(Qb + (mi * 16 + l15) * 64 + ks * 32 + quad * 8);

  f4 oacc[2][4] = {};
  float mrun[2][4], lrun[2][4];
#pragma unroll
  for (int mi = 0; mi < 2; ++mi)
#pragma unroll
    for (int r = 0; r < 4; ++r) { mrun[mi][r] = -1e30f; lrun[mi][r] = 0.f; }

  _Float16* Pw = &Ps[wave][0];

  for (int kt = 0; kt < 16; ++kt) {
    stage64(Kv + (bh * 2048 + kt * 128) * 64, 64, Ks, tid);
    stage_vt(Vt + bh * 64 * 2048 + kt * 128, Vs, tid);
    __syncthreads();

    f4 sacc[2][8] = {};
#pragma unroll
    for (int ks = 0; ks < 2; ++ks) {
      h8 kf[8];
#pragma unroll
      for (int ni = 0; ni < 8; ++ni) kf[ni] = frag64(Ks, ni * 16 + l15, ks * 4 + quad);
#pragma unroll
      for (int mi = 0; mi < 2; ++mi)
#pragma unroll
        for (int ni = 0; ni < 8; ++ni)
          sacc[mi][ni] = __builtin_amdgcn_mfma_f32_16x16x32_f16(qf[mi][ks], kf[ni], sacc[mi][ni], 0, 0, 0);
    }

    // online softmax (rows live in quad: row = mi*16 + quad*4 + r; col = ni*16 + l15)
#pragma unroll
    for (int mi = 0; mi < 2; ++mi) {
      float al[4];
#pragma unroll
      for (int r = 0; r < 4; ++r) {
        float mx = sacc[mi][0][r];
#pragma unroll
        for (int ni = 1; ni < 8; ++ni) mx = fmaxf(mx, sacc[mi][ni][r]);
#pragma unroll
        for (int dd = 1; dd < 16; dd <<= 1) mx = fmaxf(mx, __shfl_xor(mx, dd));
        float mnew = fmaxf(mrun[mi][r], mx);
        al[r] = __expf(mrun[mi][r] - mnew);
        mrun[mi][r] = mnew;
      }
      float sum[4] = {0.f, 0.f, 0.f, 0.f};
#pragma unroll
      for (int ni = 0; ni < 8; ++ni) {
        int col = ni * 16 + l15;
        int rowb = mi * 16 + quad * 4;
#pragma unroll
        for (int r = 0; r < 4; ++r) {
          float p = __expf(sacc[mi][ni][r] - mrun[mi][r]);
          sum[r] += p;
          int rr = rowb + r;
          int ch = (col >> 3) ^ (rr & 15);
          Pw[rr * 128 + ch * 8 + (col & 7)] = (_Float16)p;
        }
      }
#pragma unroll
      for (int r = 0; r < 4; ++r) {
        float s = sum[r];
#pragma unroll
        for (int dd = 1; dd < 16; dd <<= 1) s += __shfl_xor(s, dd);
        lrun[mi][r] = lrun[mi][r] * al[r] + s;
#pragma unroll
        for (int nd = 0; nd < 4; ++nd) oacc[mi][nd][r] *= al[r];
      }
    }

    // PV: A = P (per-wave LDS region), B = Vt tile
#pragma unroll
    for (int kstep = 0; kstep < 4; ++kstep) {
      h8 pa[2];
#pragma unroll
      for (int mi = 0; mi < 2; ++mi) pa[mi] = frag128(Pw, mi * 16 + l15, kstep * 4 + quad);
#pragma unroll
      for (int nd = 0; nd < 4; ++nd) {
        h8 bv = frag128(Vs, nd * 16 + l15, kstep * 4 + quad);
#pragma unroll
        for (int mi = 0; mi < 2; ++mi)
          oacc[mi][nd] = __builtin_amdgcn_mfma_f32_16x16x32_f16(pa[mi], bv, oacc[mi][nd], 0, 0, 0);
      }
    }
    __syncthreads();
  }

  int b = bh >> 4, h = bh & 15;
#pragma unroll
  for (int mi = 0; mi < 2; ++mi) {
#pragma unroll
    for (int r = 0; r < 4; ++r) {
      float inv = 1.0f / lrun[mi][r];
      int n = q0 + wave * 32 + mi * 16 + quad * 4 + r;
#pragma unroll
      for (int nd = 0; nd < 4; ++nd) {
        int d = nd * 16 + l15;
        AO[(b * 2048 + n) * 1024 + h * 64 + d] = (_Float16)(oacc[mi][nd][r] * inv);
      }
    }
  }
}

extern "C" void kernel_launch(void* const* d_in, const int* in_sizes, int n_in,
                              void* d_out, int out_size, void* d_ws, size_t ws_size,
                              hipStream_t stream) {
  const float* x = (const float*)d_in[0];
  const float* Wq = (const float*)d_in[1];
  const float* bq = (const float*)d_in[2];
  const float* Wk = (const float*)d_in[3];
  const float* bk = (const float*)d_in[4];
  const float* Wv = (const float*)d_in[5];
  const float* bv = (const float*)d_in[6];
  const float* Wo = (const float*)d_in[7];
  const float* bo = (const float*)d_in[8];
  float* out = (float*)d_out;

  char* w = (char*)d_ws;
  _Float16* xh  = (_Float16*)(w);                       // 8 MB (reused as AO after QKV)
  _Float16* Wqh = (_Float16*)(w + (8u << 20));          // 2 MB
  _Float16* Wkh = (_Float16*)(w + (10u << 20));
  _Float16* Wvh = (_Float16*)(w + (12u << 20));
  _Float16* Woh = (_Float16*)(w + (14u << 20));
  _Float16* Qh  = (_Float16*)(w + (16u << 20));         // 8 MB each
  _Float16* Kh  = (_Float16*)(w + (24u << 20));
  _Float16* Vh  = (_Float16*)(w + (32u << 20));
  _Float16* Vth = (_Float16*)(w + (40u << 20));
  _Float16* AOh = xh;

  cvt_f2h<<<4096, 256, 0, stream>>>(x, xh, 4096 * 1024);
  cvt_f2h<<<1024, 256, 0, stream>>>(Wq, Wqh, 1024 * 1024);
  cvt_f2h<<<1024, 256, 0, stream>>>(Wk, Wkh, 1024 * 1024);
  cvt_f2h<<<1024, 256, 0, stream>>>(Wv, Wvh, 1024 * 1024);
  cvt_f2h<<<1024, 256, 0, stream>>>(Wo, Woh, 1024 * 1024);

  gemm_qkv<<<dim3(8, 32, 3), 256, 0, stream>>>(xh, Wqh, Wkh, Wvh, bq, bk, bv, Qh, Kh, Vh);
  transpose_v<<<dim3(16, 32), 256, 0, stream>>>(Vh, Vth);
  attn<<<dim3(16, 32), 256, 0, stream>>>(Qh, Kh, Vth, AOh);
  gemm_out<<<dim3(8, 32), 256, 0, stream>>>(AOh, Woh, bo, out);
}

// Round 3
// 225.802 us; speedup vs baseline: 1.1438x; 1.1438x over previous
//
#include <hip/hip_runtime.h>

// MultiHeadsSelfAttention: B=2, N=2048, C=1024, H=16, D=64, SCALE=0.125
// Pipeline (all fp16 MFMA, fp32 accum/softmax):
//   cvt x,W* -> fp16 ; QKV NT-GEMM -> Q,K,V [bh][n][d] (Q pre-scaled by 2^-3)
//   V transpose -> Vt [bh][d][n] ; flash attention (S^T trick) -> AO fp16 [b][n][c]
//   final NT-GEMM AO@Wo^T + bo -> fp32 out

typedef _Float16 h8 __attribute__((ext_vector_type(8)));
typedef _Float16 h4 __attribute__((ext_vector_type(4)));
typedef float f4 __attribute__((ext_vector_type(4)));

#define AS1(p) ((const __attribute__((address_space(1))) void*)(p))
#define AS3(p) ((__attribute__((address_space(3))) void*)(p))

// Stage 128 rows x 64 halves (128B rows, 8 x 16B chunks, XOR swizzle) via global_load_lds.
__device__ __forceinline__ void stage64(const _Float16* g, int ldk, _Float16* s, int tid) {
#pragma unroll
  for (int j = 0; j < 4; ++j) {
    int off = j * 4096 + tid * 16;      // byte offset in 16KB tile; wave-uniform base + lane*16
    int row = off >> 7;
    int ch = (off >> 4) & 7;
    int gch = ch ^ (row & 7);
    __builtin_amdgcn_global_load_lds(AS1(g + row * ldk + gch * 8), AS3(s + (off >> 1)), 16, 0, 0);
  }
}

// Stage 64 rows x 128 halves (256B rows, 16 x 16B chunks, XOR swizzle); global row stride 2048.
__device__ __forceinline__ void stage_vt(const _Float16* g, _Float16* s, int tid) {
#pragma unroll
  for (int j = 0; j < 4; ++j) {
    int off = j * 4096 + tid * 16;
    int row = off >> 8;
    int ch = (off >> 4) & 15;
    int gch = ch ^ (row & 15);
    __builtin_amdgcn_global_load_lds(AS1(g + row * 2048 + gch * 8), AS3(s + (off >> 1)), 16, 0, 0);
  }
}

__device__ __forceinline__ h8 frag64(const _Float16* s, int row, int g) {
  return *(const h8*)(s + row * 64 + ((g ^ (row & 7)) << 3));
}
__device__ __forceinline__ h8 frag128(const _Float16* s, int row, int g) {
  return *(const h8*)(s + row * 128 + ((g ^ (row & 15)) << 3));
}

__global__ void cvt_f2h(const float* __restrict__ in, _Float16* __restrict__ out, int n) {
  int i = (blockIdx.x * 256 + threadIdx.x) * 4;
  if (i >= n) return;
  f4 v = *(const f4*)(in + i);
  h4 o;
  o[0] = (_Float16)v[0]; o[1] = (_Float16)v[1]; o[2] = (_Float16)v[2]; o[3] = (_Float16)v[3];
  *(h4*)(out + i) = o;
}

// NT GEMM: C[m][o] = sum_k A[m,k]*W[o,k] + bias[o]; scatter fp16 out to [b][h][n][d].
__global__ __launch_bounds__(256, 2) void gemm_qkv(
    const _Float16* __restrict__ X,
    const _Float16* __restrict__ W0, const _Float16* __restrict__ W1, const _Float16* __restrict__ W2,
    const float* __restrict__ b0, const float* __restrict__ b1, const float* __restrict__ b2,
    _Float16* __restrict__ O0, _Float16* __restrict__ O1, _Float16* __restrict__ O2) {
  __shared__ _Float16 As[128 * 64];
  __shared__ _Float16 Bs[128 * 64];
  int z = blockIdx.z;
  const _Float16* W = (z == 0) ? W0 : (z == 1) ? W1 : W2;
  const float* bias = (z == 0) ? b0 : (z == 1) ? b1 : b2;
  _Float16* Out = (z == 0) ? O0 : (z == 1) ? O1 : O2;
  float scale = (z == 0) ? 0.125f : 1.0f;  // fold SCALE=D^-0.5 into Q (exact pow2)

  int tid = threadIdx.x;
  int lane = tid & 63, wave = tid >> 6;
  int quad = lane >> 4, l15 = lane & 15;
  int wm = (wave >> 1) << 6, wn = (wave & 1) << 6;
  int m0 = blockIdx.y << 7, n0 = blockIdx.x << 7;

  f4 acc[4][4] = {};
  for (int k0 = 0; k0 < 1024; k0 += 64) {
    stage64(X + m0 * 1024 + k0, 1024, As, tid);
    stage64(W + n0 * 1024 + k0, 1024, Bs, tid);
    __syncthreads();
#pragma unroll
    for (int ks = 0; ks < 2; ++ks) {
      h8 af[4], bf[4];
#pragma unroll
      for (int i = 0; i < 4; ++i) af[i] = frag64(As, wm + i * 16 + l15, ks * 4 + quad);
#pragma unroll
      for (int i = 0; i < 4; ++i) bf[i] = frag64(Bs, wn + i * 16 + l15, ks * 4 + quad);
#pragma unroll
      for (int mi = 0; mi < 4; ++mi)
#pragma unroll
        for (int ni = 0; ni < 4; ++ni)
          acc[mi][ni] = __builtin_amdgcn_mfma_f32_16x16x32_f16(af[mi], bf[ni], acc[mi][ni], 0, 0, 0);
    }
    __syncthreads();
  }
#pragma unroll
  for (int mi = 0; mi < 4; ++mi) {
#pragma unroll
    for (int ni = 0; ni < 4; ++ni) {
      int o = n0 + wn + ni * 16 + l15;
      float bv = bias[o];
      int h = o >> 6, d = o & 63;
#pragma unroll
      for (int r = 0; r < 4; ++r) {
        int m = m0 + wm + mi * 16 + quad * 4 + r;   // C layout: col=lane&15, row=quad*4+reg
        int b = m >> 11, n = m & 2047;
        float v = (acc[mi][ni][r] + bv) * scale;
        Out[(((b * 16 + h) * 2048 + n) << 6) + d] = (_Float16)v;
      }
    }
  }
}

// Final NT GEMM: out fp32 [m][1024].
__global__ __launch_bounds__(256, 2) void gemm_out(
    const _Float16* __restrict__ A, const _Float16* __restrict__ W,
    const float* __restrict__ bias, float* __restrict__ Out) {
  __shared__ _Float16 As[128 * 64];
  __shared__ _Float16 Bs[128 * 64];
  int tid = threadIdx.x;
  int lane = tid & 63, wave = tid >> 6;
  int quad = lane >> 4, l15 = lane & 15;
  int wm = (wave >> 1) << 6, wn = (wave & 1) << 6;
  int m0 = blockIdx.y << 7, n0 = blockIdx.x << 7;

  f4 acc[4][4] = {};
  for (int k0 = 0; k0 < 1024; k0 += 64) {
    stage64(A + m0 * 1024 + k0, 1024, As, tid);
    stage64(W + n0 * 1024 + k0, 1024, Bs, tid);
    __syncthreads();
#pragma unroll
    for (int ks = 0; ks < 2; ++ks) {
      h8 af[4], bf[4];
#pragma unroll
      for (int i = 0; i < 4; ++i) af[i] = frag64(As, wm + i * 16 + l15, ks * 4 + quad);
#pragma unroll
      for (int i = 0; i < 4; ++i) bf[i] = frag64(Bs, wn + i * 16 + l15, ks * 4 + quad);
#pragma unroll
      for (int mi = 0; mi < 4; ++mi)
#pragma unroll
        for (int ni = 0; ni < 4; ++ni)
          acc[mi][ni] = __builtin_amdgcn_mfma_f32_16x16x32_f16(af[mi], bf[ni], acc[mi][ni], 0, 0, 0);
    }
    __syncthreads();
  }
#pragma unroll
  for (int mi = 0; mi < 4; ++mi) {
#pragma unroll
    for (int ni = 0; ni < 4; ++ni) {
      int o = n0 + wn + ni * 16 + l15;
      float bv = bias[o];
#pragma unroll
      for (int r = 0; r < 4; ++r) {
        int m = m0 + wm + mi * 16 + quad * 4 + r;
        Out[m * 1024 + o] = acc[mi][ni][r] + bv;
      }
    }
  }
}

// V [bh][n][d] -> Vt [bh][d][n], 128-key tiles, LDS chunk-swizzled transpose.
__global__ __launch_bounds__(256) void transpose_v(const _Float16* __restrict__ V,
                                                   _Float16* __restrict__ Vt) {
  __shared__ _Float16 t[64 * 128];
  int tid = threadIdx.x;
  int bh = blockIdx.y, n0 = blockIdx.x << 7;
  const _Float16* src = V + (bh * 2048 + n0) * 64;
#pragma unroll
  for (int j = 0; j < 4; ++j) {
    int c = j * 256 + tid;
    int n = c >> 3, dc = (c & 7) * 8;
    h8 v = *(const h8*)(src + n * 64 + dc);
#pragma unroll
    for (int e = 0; e < 8; ++e) {
      int d = dc + e;
      t[d * 128 + ((((n >> 3) ^ (d & 15))) << 3) + (n & 7)] = v[e];
    }
  }
  __syncthreads();
#pragma unroll
  for (int j = 0; j < 4; ++j) {
    int c = j * 256 + tid;
    int d = c >> 4, nc = (c & 15) * 8;
    h8 v = *(const h8*)(t + d * 128 + ((((nc >> 3) ^ (d & 15))) << 3));
    *(h8*)(Vt + (bh * 64 + d) * 2048 + n0 + nc) = v;
  }
}

// Flash attention, S^T operand-swap form.
// Grid: (32 q-tiles of 64 rows, 32 bh). 4 waves x 16 q-rows. K-tiles of 128 keys,
// processed as two 64-key online-softmax sub-iterations.
// QK^T computed transposed: sacc = mfma(A=kf, B=qf) -> S^T[key][qrow], qrow = l15.
// Softmax state (mrun/lrun/al) is per-lane, indexed by qrow = l15.
// O accumulator is C-layout: row = quad*4+r -> alpha rescale and l must be
// cross-indexed via __shfl(x, quad*4+r) (al/lrun are quad-uniform after the
// 16/32 xor-reduction, so lane quad*4+r holds the value for qrow quad*4+r).
__global__ __launch_bounds__(256, 4) void attn(
    const _Float16* __restrict__ Q, const _Float16* __restrict__ Kv,
    const _Float16* __restrict__ Vt, _Float16* __restrict__ AO) {
  __shared__ _Float16 Ks[128 * 64];   // 16 KB: K[key][dk], chunk-swizzled
  __shared__ _Float16 Vs[64 * 128];   // 16 KB: Vt[d][key], chunk-swizzled
  __shared__ _Float16 Ps[4][16 * 64]; // 8 KB: per-wave P[qrow][key_loc], chunk-swizzled
  int tid = threadIdx.x, lane = tid & 63, wave = tid >> 6;
  int quad = lane >> 4, l15 = lane & 15;
  int bh = blockIdx.y, q0 = blockIdx.x << 6;

  const _Float16* Qb = Q + (bh * 2048 + q0 + wave * 16) * 64;
  h8 qf[2];
#pragma unroll
  for (int ks = 0; ks < 2; ++ks)
    qf[ks] = *(const h8*)(Qb + l15 * 64 + ks * 32 + quad * 8);

  f4 oacc[4] = {};
  float mrun = -1e30f, lrun = 0.f;
  _Float16* Pw = &Ps[wave][0];

  for (int kt = 0; kt < 16; ++kt) {
    stage64(Kv + (bh * 2048 + kt * 128) * 64, 64, Ks, tid);
    stage_vt(Vt + bh * 64 * 2048 + kt * 128, Vs, tid);
    __syncthreads();

#pragma unroll
    for (int sub = 0; sub < 2; ++sub) {
      // S^T = K . Q^T over 64 keys: C[key_loc = ni*16+quad*4+r][qrow = l15]
      f4 sacc[4] = {};
#pragma unroll
      for (int ks = 0; ks < 2; ++ks) {
        h8 kf[4];
#pragma unroll
        for (int ni = 0; ni < 4; ++ni)
          kf[ni] = frag64(Ks, sub * 64 + ni * 16 + l15, ks * 4 + quad);
#pragma unroll
        for (int ni = 0; ni < 4; ++ni)
          sacc[ni] = __builtin_amdgcn_mfma_f32_16x16x32_f16(kf[ni], qf[ks], sacc[ni], 0, 0, 0);
      }

      // online softmax for qrow = l15 (per-lane scalars; cross-quad = keys)
      float mx = sacc[0][0];
#pragma unroll
      for (int ni = 0; ni < 4; ++ni)
#pragma unroll
        for (int r = 0; r < 4; ++r) mx = fmaxf(mx, sacc[ni][r]);
      mx = fmaxf(mx, __shfl_xor(mx, 16));
      mx = fmaxf(mx, __shfl_xor(mx, 32));
      float mnew = fmaxf(mrun, mx);
      float al = __expf(mrun - mnew);
      mrun = mnew;

      float sum = 0.f;
#pragma unroll
      for (int ni = 0; ni < 4; ++ni) {
        h4 pk;
#pragma unroll
        for (int r = 0; r < 4; ++r) {
          float p = __expf(sacc[ni][r] - mnew);
          sum += p;
          pk[r] = (_Float16)p;
        }
        int chunk = ni * 2 + (quad >> 1);            // 16B chunk in 64-half row
        *(h4*)(Pw + l15 * 64 + ((chunk ^ (l15 & 7)) << 3) + ((quad & 1) << 2)) = pk;
      }
      sum += __shfl_xor(sum, 16);
      sum += __shfl_xor(sum, 32);
      lrun = lrun * al + sum;

      // Rescale O: oacc row = quad*4+r, so fetch that row's alpha (quad-uniform).
      float alr[4];
#pragma unroll
      for (int r = 0; r < 4; ++r) alr[r] = __shfl(al, quad * 4 + r);
#pragma unroll
      for (int nd = 0; nd < 4; ++nd)
#pragma unroll
        for (int r = 0; r < 4; ++r) oacc[nd][r] *= alr[r];

      // PV over these 64 keys: A = P (per-wave LDS), B = Vt tile
#pragma unroll
      for (int ks2 = 0; ks2 < 2; ++ks2) {
        h8 pa = *(const h8*)(Pw + l15 * 64 + (((ks2 * 4 + quad) ^ (l15 & 7)) << 3));
#pragma unroll
        for (int nd = 0; nd < 4; ++nd) {
          h8 vf = frag128(Vs, nd * 16 + l15, sub * 8 + ks2 * 4 + quad);
          oacc[nd] = __builtin_amdgcn_mfma_f32_16x16x32_f16(pa, vf, oacc[nd], 0, 0, 0);
        }
      }
    }
    __syncthreads();
  }

  // Epilogue: O rows = quad*4+r (C layout); l for that row lives at lane l15==row.
  int b = bh >> 4, h = bh & 15;
#pragma unroll
  for (int r = 0; r < 4; ++r) {
    float lr = __shfl(lrun, quad * 4 + r);
    float inv = 1.0f / lr;
    int n = q0 + wave * 16 + quad * 4 + r;
#pragma unroll
    for (int nd = 0; nd < 4; ++nd) {
      int d = nd * 16 + l15;
      AO[(b * 2048 + n) * 1024 + h * 64 + d] = (_Float16)(oacc[nd][r] * inv);
    }
  }
}

extern "C" void kernel_launch(void* const* d_in, const int* in_sizes, int n_in,
                              void* d_out, int out_size, void* d_ws, size_t ws_size,
                              hipStream_t stream) {
  const float* x = (const float*)d_in[0];
  const float* Wq = (const float*)d_in[1];
  const float* bq = (const float*)d_in[2];
  const float* Wk = (const float*)d_in[3];
  const float* bk = (const float*)d_in[4];
  const float* Wv = (const float*)d_in[5];
  const float* bv = (const float*)d_in[6];
  const float* Wo = (const float*)d_in[7];
  const float* bo = (const float*)d_in[8];
  float* out = (float*)d_out;

  char* w = (char*)d_ws;
  _Float16* xh  = (_Float16*)(w);                       // 8 MB (reused as AO after QKV)
  _Float16* Wqh = (_Float16*)(w + (8u << 20));          // 2 MB
  _Float16* Wkh = (_Float16*)(w + (10u << 20));
  _Float16* Wvh = (_Float16*)(w + (12u << 20));
  _Float16* Woh = (_Float16*)(w + (14u << 20));
  _Float16* Qh  = (_Float16*)(w + (16u << 20));         // 8 MB each
  _Float16* Kh  = (_Float16*)(w + (24u << 20));
  _Float16* Vh  = (_Float16*)(w + (32u << 20));
  _Float16* Vth = (_Float16*)(w + (40u << 20));
  _Float16* AOh = xh;

  cvt_f2h<<<4096, 256, 0, stream>>>(x, xh, 4096 * 1024);
  cvt_f2h<<<1024, 256, 0, stream>>>(Wq, Wqh, 1024 * 1024);
  cvt_f2h<<<1024, 256, 0, stream>>>(Wk, Wkh, 1024 * 1024);
  cvt_f2h<<<1024, 256, 0, stream>>>(Wv, Wvh, 1024 * 1024);
  cvt_f2h<<<1024, 256, 0, stream>>>(Wo, Woh, 1024 * 1024);

  gemm_qkv<<<dim3(8, 32, 3), 256, 0, stream>>>(xh, Wqh, Wkh, Wvh, bq, bk, bv, Qh, Kh, Vh);
  transpose_v<<<dim3(16, 32), 256, 0, stream>>>(Vh, Vth);
  attn<<<dim3(32, 32), 256, 0, stream>>>(Qh, Kh, Vth, AOh);
  gemm_out<<<dim3(8, 32), 256, 0, stream>>>(AOh, Woh, bo, out);
}

// Round 4
// 190.201 us; speedup vs baseline: 1.3579x; 1.1872x over previous
//
#include <hip/hip_runtime.h>
#include <stdint.h>

// MultiHeadsSelfAttention: B=2, N=2048, C=1024, H=16, D=64, SCALE=0.125
// fp16 MFMA everywhere, fp32 accum/softmax.
//   cvt_all: x,W* -> fp16 (one launch)
//   gemm_qkv: Q (scaled by SCALE*log2e, exp2-domain softmax), K -> [bh][n][d]; V -> Vt [bh][d][n]
//   attn: flash, S^T operand-swap + permuted-K-row trick => P stays in registers,
//         PV computed as O^T = Vt . P^T  (LDS traffic = kf+vf only)
//   gemm_out: AO @ Wo^T + bo -> fp32

typedef _Float16 h8 __attribute__((ext_vector_type(8)));
typedef _Float16 h4 __attribute__((ext_vector_type(4)));
typedef _Float16 h2 __attribute__((ext_vector_type(2)));
typedef float f4 __attribute__((ext_vector_type(4)));
typedef uint32_t u32;
typedef u32 u32x4 __attribute__((ext_vector_type(4)));

#define AS1(p) ((const __attribute__((address_space(1))) void*)(p))
#define AS3(p) ((__attribute__((address_space(3))) void*)(p))

// Stage ITERS*32 rows of 128 B (8 x 16B chunks, XOR swizzle) via global_load_lds.
template <int ITERS>
__device__ __forceinline__ void stage128B(const _Float16* g, int ldk, _Float16* s, int tid) {
#pragma unroll
  for (int j = 0; j < ITERS; ++j) {
    int off = j * 4096 + tid * 16;
    int row = off >> 7;
    int ch = (off >> 4) & 7;
    int gch = ch ^ (row & 7);
    __builtin_amdgcn_global_load_lds(AS1(g + row * ldk + gch * 8), AS3(s + (off >> 1)), 16, 0, 0);
  }
}

// Stage 64 rows x 256 B (16 x 16B chunks, XOR swizzle); global row stride 2048.
__device__ __forceinline__ void stage_vt(const _Float16* g, _Float16* s, int tid) {
#pragma unroll
  for (int j = 0; j < 4; ++j) {
    int off = j * 4096 + tid * 16;
    int row = off >> 8;
    int ch = (off >> 4) & 15;
    int gch = ch ^ (row & 15);
    __builtin_amdgcn_global_load_lds(AS1(g + row * 2048 + gch * 8), AS3(s + (off >> 1)), 16, 0, 0);
  }
}

__device__ __forceinline__ h8 frag64(const _Float16* s, int row, int g) {
  return *(const h8*)(s + row * 64 + ((g ^ (row & 7)) << 3));
}
__device__ __forceinline__ h8 frag128(const _Float16* s, int row, int g) {
  return *(const h8*)(s + row * 128 + ((g ^ (row & 15)) << 3));
}

// One fused cast kernel: x (4096 blk) + Wq/Wk/Wv/Wo (1024 blk each).
__global__ void cvt_all(const float* __restrict__ x, const float* __restrict__ Wq,
                        const float* __restrict__ Wk, const float* __restrict__ Wv,
                        const float* __restrict__ Wo, _Float16* __restrict__ xh,
                        _Float16* __restrict__ q, _Float16* __restrict__ k,
                        _Float16* __restrict__ v, _Float16* __restrict__ o) {
  int blk = blockIdx.x;
  const float* src; _Float16* dst; int off;
  if (blk < 4096)      { src = x;  dst = xh; off = blk; }
  else if (blk < 5120) { src = Wq; dst = q;  off = blk - 4096; }
  else if (blk < 6144) { src = Wk; dst = k;  off = blk - 5120; }
  else if (blk < 7168) { src = Wv; dst = v;  off = blk - 6144; }
  else                 { src = Wo; dst = o;  off = blk - 7168; }
  int i = off * 1024 + threadIdx.x * 4;
  f4 vv = *(const f4*)(src + i);
  h4 ov;
  ov[0] = (_Float16)vv[0]; ov[1] = (_Float16)vv[1]; ov[2] = (_Float16)vv[2]; ov[3] = (_Float16)vv[3];
  *(h4*)(dst + i) = ov;
}

// NT GEMM x@W^T+b. z=0: Q scaled by SCALE*log2e -> [bh][n][d]; z=1: K -> [bh][n][d];
// z=2: V written directly transposed -> Vt [bh][d][n] (b64 stores, replaces transpose_v).
__global__ __launch_bounds__(256, 2) void gemm_qkv(
    const _Float16* __restrict__ X,
    const _Float16* __restrict__ W0, const _Float16* __restrict__ W1, const _Float16* __restrict__ W2,
    const float* __restrict__ b0, const float* __restrict__ b1, const float* __restrict__ b2,
    _Float16* __restrict__ O0, _Float16* __restrict__ O1, _Float16* __restrict__ O2) {
  __shared__ _Float16 As[128 * 64];
  __shared__ _Float16 Bs[128 * 64];
  int z = blockIdx.z;
  const _Float16* W = (z == 0) ? W0 : (z == 1) ? W1 : W2;
  const float* bias = (z == 0) ? b0 : (z == 1) ? b1 : b2;

  int tid = threadIdx.x;
  int lane = tid & 63, wave = tid >> 6;
  int quad = lane >> 4, l15 = lane & 15;
  int wm = (wave >> 1) << 6, wn = (wave & 1) << 6;
  int m0 = blockIdx.y << 7, n0 = blockIdx.x << 7;

  f4 acc[4][4] = {};
  for (int k0 = 0; k0 < 1024; k0 += 64) {
    stage128B<4>(X + m0 * 1024 + k0, 1024, As, tid);
    stage128B<4>(W + n0 * 1024 + k0, 1024, Bs, tid);
    __syncthreads();
#pragma unroll
    for (int ks = 0; ks < 2; ++ks) {
      h8 af[4], bf[4];
#pragma unroll
      for (int i = 0; i < 4; ++i) af[i] = frag64(As, wm + i * 16 + l15, ks * 4 + quad);
#pragma unroll
      for (int i = 0; i < 4; ++i) bf[i] = frag64(Bs, wn + i * 16 + l15, ks * 4 + quad);
#pragma unroll
      for (int mi = 0; mi < 4; ++mi)
#pragma unroll
        for (int ni = 0; ni < 4; ++ni)
          acc[mi][ni] = __builtin_amdgcn_mfma_f32_16x16x32_f16(af[mi], bf[ni], acc[mi][ni], 0, 0, 0);
    }
    __syncthreads();
  }

  if (z == 2) {
    // Vt[bh][d][n]: lane's 4 r-values = 4 consecutive n -> one b64 store.
#pragma unroll
    for (int mi = 0; mi < 4; ++mi) {
#pragma unroll
      for (int ni = 0; ni < 4; ++ni) {
        int o = n0 + wn + ni * 16 + l15;
        float bv = bias[o];
        int h = o >> 6, dd = o & 63;
        int m = m0 + wm + mi * 16 + quad * 4;
        int b = m >> 11, n = m & 2047;
        h4 v;
#pragma unroll
        for (int r = 0; r < 4; ++r) v[r] = (_Float16)(acc[mi][ni][r] + bv);
        *(h4*)(O2 + (((b * 16 + h) * 64 + dd) * 2048 + n)) = v;
      }
    }
  } else {
    float scale = (z == 0) ? 0.125f * 1.44269504089f : 1.0f;  // fold SCALE*log2e into Q
    _Float16* Out = (z == 0) ? O0 : O1;
#pragma unroll
    for (int mi = 0; mi < 4; ++mi) {
#pragma unroll
      for (int ni = 0; ni < 4; ++ni) {
        int o = n0 + wn + ni * 16 + l15;
        float bv = bias[o];
        int h = o >> 6, d = o & 63;
#pragma unroll
        for (int r = 0; r < 4; ++r) {
          int m = m0 + wm + mi * 16 + quad * 4 + r;  // C layout: col=lane&15, row=quad*4+reg
          int b = m >> 11, n = m & 2047;
          float v = (acc[mi][ni][r] + bv) * scale;
          Out[(((b * 16 + h) * 2048 + n) << 6) + d] = (_Float16)v;
        }
      }
    }
  }
}

// Final NT GEMM 128x64 tiles (512 blocks): out fp32 [m][1024].
__global__ __launch_bounds__(256, 2) void gemm_out(
    const _Float16* __restrict__ A, const _Float16* __restrict__ W,
    const float* __restrict__ bias, float* __restrict__ Out) {
  __shared__ _Float16 As[128 * 64];
  __shared__ _Float16 Bs[64 * 64];
  int tid = threadIdx.x;
  int lane = tid & 63, wave = tid >> 6;
  int quad = lane >> 4, l15 = lane & 15;
  int wm = (wave >> 1) << 6, wn = (wave & 1) << 5;
  int m0 = blockIdx.y << 7, n0 = blockIdx.x << 6;

  f4 acc[4][2] = {};
  for (int k0 = 0; k0 < 1024; k0 += 64) {
    stage128B<4>(A + m0 * 1024 + k0, 1024, As, tid);
    stage128B<2>(W + n0 * 1024 + k0, 1024, Bs, tid);
    __syncthreads();
#pragma unroll
    for (int ks = 0; ks < 2; ++ks) {
      h8 af[4], bf[2];
#pragma unroll
      for (int i = 0; i < 4; ++i) af[i] = frag64(As, wm + i * 16 + l15, ks * 4 + quad);
#pragma unroll
      for (int i = 0; i < 2; ++i) bf[i] = frag64(Bs, wn + i * 16 + l15, ks * 4 + quad);
#pragma unroll
      for (int mi = 0; mi < 4; ++mi)
#pragma unroll
        for (int ni = 0; ni < 2; ++ni)
          acc[mi][ni] = __builtin_amdgcn_mfma_f32_16x16x32_f16(af[mi], bf[ni], acc[mi][ni], 0, 0, 0);
    }
    __syncthreads();
  }
#pragma unroll
  for (int mi = 0; mi < 4; ++mi) {
#pragma unroll
    for (int ni = 0; ni < 2; ++ni) {
      int o = n0 + wn + ni * 16 + l15;
      float bv = bias[o];
#pragma unroll
      for (int r = 0; r < 4; ++r) {
        int m = m0 + wm + mi * 16 + quad * 4 + r;
        Out[m * 1024 + o] = acc[mi][ni][r] + bv;
      }
    }
  }
}

// Flash attention. Grid (16, 32): 128 qrows/block, 4 waves x (2 sets of 16 qrows).
// QK^T transposed (A=kf,B=qf) -> S^T[key][qrow], qrow=l15. kf A-frag rows are PERMUTED:
//   slot(ni, l15) -> true key (ni>>1)*32 + (l15>>2)*8 + (ni&1)*4 + (l15&3)
// so the C-layout S^T fragments, packed pairwise (cvt_pkrtz), ARE the PV B-operand
// (P^T) in-lane: pb VGPR j for kstep t = pkw[4t+j]. PV: O^T = Vt . P^T (A=vf).
// O^T cols = qrow = l15 -> softmax state, alpha rescale, 1/l all per-lane.
__global__ __launch_bounds__(256, 2) void attn(
    const _Float16* __restrict__ Q, const _Float16* __restrict__ Kv,
    const _Float16* __restrict__ Vt, _Float16* __restrict__ AO) {
  __shared__ _Float16 Ks[128 * 64];   // 16 KB
  __shared__ _Float16 Vs[64 * 128];   // 16 KB
  int tid = threadIdx.x, lane = tid & 63, wave = tid >> 6;
  int quad = lane >> 4, l15 = lane & 15;
  int bh = blockIdx.y, q0 = blockIdx.x << 7;

  h8 qf[2][2];
#pragma unroll
  for (int s = 0; s < 2; ++s) {
    const _Float16* Qb = Q + (bh * 2048 + q0 + wave * 32 + s * 16) * 64;
#pragma unroll
    for (int ks = 0; ks < 2; ++ks)
      qf[s][ks] = *(const h8*)(Qb + l15 * 64 + ks * 32 + quad * 8);
  }

  f4 oacc[2][4] = {};
  float mrun[2] = {-1e30f, -1e30f}, lrun[2] = {0.f, 0.f};
  int pbase = ((l15 >> 2) << 3) + (l15 & 3);  // permuted-row base

  for (int kt = 0; kt < 16; ++kt) {
    stage128B<4>(Kv + (bh * 2048 + kt * 128) * 64, 64, Ks, tid);
    stage_vt(Vt + bh * 131072 + kt * 128, Vs, tid);
    __syncthreads();

    // S^T over 128 keys, both q-sets, permuted key slots.
    f4 sacc[2][8] = {};
#pragma unroll
    for (int ks = 0; ks < 2; ++ks) {
#pragma unroll
      for (int ni = 0; ni < 8; ++ni) {
        int prow = ((ni >> 1) << 5) + ((ni & 1) << 2) + pbase;
        h8 kf = frag64(Ks, prow, ks * 4 + quad);
        sacc[0][ni] = __builtin_amdgcn_mfma_f32_16x16x32_f16(kf, qf[0][ks], sacc[0][ni], 0, 0, 0);
        sacc[1][ni] = __builtin_amdgcn_mfma_f32_16x16x32_f16(kf, qf[1][ks], sacc[1][ni], 0, 0, 0);
      }
    }

    // Online softmax (exp2 domain), P packed in-register.
    u32 pkw[2][16];
#pragma unroll
    for (int s = 0; s < 2; ++s) {
      float mx = sacc[s][0][0];
#pragma unroll
      for (int ni = 0; ni < 8; ++ni)
#pragma unroll
        for (int r = 0; r < 4; ++r) mx = fmaxf(mx, sacc[s][ni][r]);
      mx = fmaxf(mx, __shfl_xor(mx, 16));
      mx = fmaxf(mx, __shfl_xor(mx, 32));
      float mnew = fmaxf(mrun[s], mx);
      float al = __builtin_amdgcn_exp2f(mrun[s] - mnew);
      mrun[s] = mnew;
      float sum = 0.f;
#pragma unroll
      for (int ni = 0; ni < 8; ++ni) {
        float p0 = __builtin_amdgcn_exp2f(sacc[s][ni][0] - mnew);
        float p1 = __builtin_amdgcn_exp2f(sacc[s][ni][1] - mnew);
        float p2 = __builtin_amdgcn_exp2f(sacc[s][ni][2] - mnew);
        float p3 = __builtin_amdgcn_exp2f(sacc[s][ni][3] - mnew);
        sum += (p0 + p1) + (p2 + p3);
        pkw[s][ni * 2 + 0] = __builtin_bit_cast(u32, __builtin_amdgcn_cvt_pkrtz(p0, p1));
        pkw[s][ni * 2 + 1] = __builtin_bit_cast(u32, __builtin_amdgcn_cvt_pkrtz(p2, p3));
      }
      sum += __shfl_xor(sum, 16);
      sum += __shfl_xor(sum, 32);
      lrun[s] = lrun[s] * al + sum;
#pragma unroll
      for (int nd = 0; nd < 4; ++nd) oacc[s][nd] *= al;   // per-lane al (col=qrow=l15)
    }

    // PV: O^T += Vt . P^T ; vf shared across both q-sets.
#pragma unroll
    for (int t = 0; t < 4; ++t) {
      h8 vf[4];
#pragma unroll
      for (int nd = 0; nd < 4; ++nd) vf[nd] = frag128(Vs, nd * 16 + l15, t * 4 + quad);
#pragma unroll
      for (int s = 0; s < 2; ++s) {
        u32x4 pw = {pkw[s][4 * t + 0], pkw[s][4 * t + 1], pkw[s][4 * t + 2], pkw[s][4 * t + 3]};
        h8 pb = __builtin_bit_cast(h8, pw);
#pragma unroll
        for (int nd = 0; nd < 4; ++nd)
          oacc[s][nd] = __builtin_amdgcn_mfma_f32_16x16x32_f16(vf[nd], pb, oacc[s][nd], 0, 0, 0);
      }
    }
    __syncthreads();
  }

  // Epilogue: O^T C-frag row = d = nd*16+quad*4+r, col = qrow = l15 -> b64 stores.
  int b = bh >> 4, h = bh & 15;
#pragma unroll
  for (int s = 0; s < 2; ++s) {
    float inv = 1.0f / lrun[s];
    int n = q0 + wave * 32 + s * 16 + l15;
    _Float16* base = AO + (b * 2048 + n) * 1024 + h * 64;
#pragma unroll
    for (int nd = 0; nd < 4; ++nd) {
      h4 o;
#pragma unroll
      for (int r = 0; r < 4; ++r) o[r] = (_Float16)(oacc[s][nd][r] * inv);
      *(h4*)(base + nd * 16 + quad * 4) = o;
    }
  }
}

extern "C" void kernel_launch(void* const* d_in, const int* in_sizes, int n_in,
                              void* d_out, int out_size, void* d_ws, size_t ws_size,
                              hipStream_t stream) {
  const float* x = (const float*)d_in[0];
  const float* Wq = (const float*)d_in[1];
  const float* bq = (const float*)d_in[2];
  const float* Wk = (const float*)d_in[3];
  const float* bk = (const float*)d_in[4];
  const float* Wv = (const float*)d_in[5];
  const float* bv = (const float*)d_in[6];
  const float* Wo = (const float*)d_in[7];
  const float* bo = (const float*)d_in[8];
  float* out = (float*)d_out;

  char* w = (char*)d_ws;
  _Float16* xh  = (_Float16*)(w);                // 8 MB (reused as AO after gemm_qkv)
  _Float16* Wqh = (_Float16*)(w + (8u << 20));   // 2 MB each
  _Float16* Wkh = (_Float16*)(w + (10u << 20));
  _Float16* Wvh = (_Float16*)(w + (12u << 20));
  _Float16* Woh = (_Float16*)(w + (14u << 20));
  _Float16* Qh  = (_Float16*)(w + (16u << 20));  // 8 MB each
  _Float16* Kh  = (_Float16*)(w + (24u << 20));
  _Float16* Vth = (_Float16*)(w + (32u << 20));
  _Float16* AOh = xh;

  cvt_all<<<8192, 256, 0, stream>>>(x, Wq, Wk, Wv, Wo, xh, Wqh, Wkh, Wvh, Woh);
  gemm_qkv<<<dim3(8, 32, 3), 256, 0, stream>>>(xh, Wqh, Wkh, Wvh, bq, bk, bv, Qh, Kh, Vth);
  attn<<<dim3(16, 32), 256, 0, stream>>>(Qh, Kh, Vth, AOh);
  gemm_out<<<dim3(16, 32), 256, 0, stream>>>(AOh, Woh, bo, out);
}